// Round 2
// baseline (242.818 us; speedup 1.0000x reference)
//
#include <hip/hip_runtime.h>
#include <hip/hip_bf16.h>

typedef short bs8 __attribute__((ext_vector_type(8)));
typedef short bs4 __attribute__((ext_vector_type(4)));
typedef float f32x4 __attribute__((ext_vector_type(4)));

#define B_ 4
#define L_ 2048
#define H_ 16
#define E_ 64
#define QT_ 128   // q rows per block (4 row-bands x 32 rows, 2 strips of 16)
#define KTS 128   // keys per staged super-tile (split across 2 wave groups)
#define KSTR 72   // LDS stride (shorts) for K tile rows
#define VSTR 136  // LDS stride (shorts) for V tile rows (128 keys + pad)
#define PSTR 76   // LDS stride (shorts) for P scratch
#define OSTR 68   // f32 stride for combine scratch
#define NEG_INF (-1e30f)
#define SCALE_LOG2E (0.125f * 1.44269504088896340736f)

__device__ __forceinline__ short bf16of(float x) {
  __hip_bfloat16 h = __float2bfloat16(x);
  return *reinterpret_cast<short*>(&h);
}

// ---------- Fused prepass ----------
// blocks [0,1024):    K fp32 [b,s,h,e] -> bf16 Kb [bh,s,e]   (grid-stride x8)
// blocks [1024,3072): V fp32 [b,s,h,e] -> bf16 Vt [bh,e,s]   (packed-u32 LDS transpose)
__global__ __launch_bounds__(256) void prep(const float* __restrict__ K,
                                            const float* __restrict__ V,
                                            short* __restrict__ Kb,
                                            short* __restrict__ Vt) {
  __shared__ unsigned int lt[64 * 35];   // [e][s_pair] packed 2x bf16
  const int tid = threadIdx.x;
  if (blockIdx.x < 1024) {
    size_t base = (size_t)blockIdx.x * 256 + tid;
#pragma unroll
    for (int i = 0; i < 8; ++i) {
      size_t g = base + (size_t)i * 262144;   // float4 index
      int e4 = g & 15;
      int h  = (g >> 4) & 15;
      int s  = (g >> 8) & 2047;
      int b  = (int)(g >> 19);
      float4 v = *(const float4*)(K + g * 4);
      bs4 o;
      o.x = bf16of(v.x); o.y = bf16of(v.y); o.z = bf16of(v.z); o.w = bf16of(v.w);
      *(bs4*)(Kb + (((size_t)(b * 16 + h) * L_ + s) * E_ + e4 * 4)) = o;
    }
  } else {
    int vb = blockIdx.x - 1024;   // 0..2047
    int st = vb & 31, bh = vb >> 5;
    int b = bh >> 4, h = bh & 15;
    int s0 = st * 64;
#pragma unroll
    for (int i = 0; i < 2; ++i) {
      int idx = i * 256 + tid;       // 0..511
      int sp = idx >> 4;             // s-pair 0..31
      int e4 = idx & 15;
      const float* p0 = V + (((size_t)b * L_ + s0 + 2 * sp) * H_ + h) * E_ + e4 * 4;
      float4 v0 = *(const float4*)p0;
      float4 v1 = *(const float4*)(p0 + H_ * E_);
      unsigned u;
      u = (unsigned short)bf16of(v0.x) | ((unsigned)(unsigned short)bf16of(v1.x) << 16);
      lt[(e4 * 4 + 0) * 35 + sp] = u;
      u = (unsigned short)bf16of(v0.y) | ((unsigned)(unsigned short)bf16of(v1.y) << 16);
      lt[(e4 * 4 + 1) * 35 + sp] = u;
      u = (unsigned short)bf16of(v0.z) | ((unsigned)(unsigned short)bf16of(v1.z) << 16);
      lt[(e4 * 4 + 2) * 35 + sp] = u;
      u = (unsigned short)bf16of(v0.w) | ((unsigned)(unsigned short)bf16of(v1.w) << 16);
      lt[(e4 * 4 + 3) * 35 + sp] = u;
    }
    __syncthreads();
#pragma unroll
    for (int i = 0; i < 2; ++i) {
      int idx = i * 256 + tid;
      int e  = idx >> 3;             // 0..63
      int s8 = idx & 7;              // 8-key group
      uint4 o;
      o.x = lt[e * 35 + s8 * 4 + 0];
      o.y = lt[e * 35 + s8 * 4 + 1];
      o.z = lt[e * 35 + s8 * 4 + 2];
      o.w = lt[e * 35 + s8 * 4 + 3];
      *(uint4*)(Vt + ((size_t)bh * E_ + e) * L_ + s0 + 8 * s8) = o;
    }
  }
}

// ---------- Main flash-attention kernel ----------
// Grid 512, 512 threads (8 waves). Block handles 128-row q-tile pair
// {p, 15-p}: 17 super-tiles of 128 keys -> perfectly balanced.
// Split-K: waves 0-3 (group A) process keys [k0,k0+64), waves 4-7 (B)
// keys [k0+64,k0+128) of the same staged super-tile; partial accO/accL
// (unnormalized, exp2 domain) combined via LDS at phase end.
// Wave (g,wl) owns rows [q0+32wl, +32) as 2 strips of 16 -> K/V frag
// reads amortized across strips (r0 efficiency), 2 blocks/CU x 8 waves
// = 4 waves/SIMD (2x r0 concurrency).
// XCD decode: id%8 = XCD; each XCD works bh in [x*8,x*8+8) (K/V L2-local).
// Layouts (verified m89/m91/m120):
//   A-frag:  A[m = lane&15][k = quad*8 + j]
//   B-frag:  B[k = quad*8 + j][n = lane&15]
//   C/D:     row = quad*4 + reg, col = lane&15
__global__ __launch_bounds__(512, 4) void flash_fwd(const float* __restrict__ Q,
                                                    const short* __restrict__ Kb,
                                                    const short* __restrict__ Vt,
                                                    float* __restrict__ O) {
  const int id = blockIdx.x;          // 0..511
  const int s  = id >> 3;             // 0..63 within XCD
  const int bh = (id & 7) * 8 + (s >> 3);
  const int p  = s & 7;               // pair {p, 15-p}
  const int b = bh >> 4, h = bh & 15;
  const int tid = threadIdx.x;
  const int w8 = tid >> 6;            // wave 0..7
  const int g  = w8 >> 2;             // key group: 0 -> [k0,k0+64), 1 -> [k0+64,k0+128)
  const int wl = w8 & 3;              // row band [q0+32wl, +32)
  const int lane = tid & 63;
  const int quad = lane >> 4;
  const int l16 = lane & 15;

  __shared__ short ldsK[KTS * KSTR];       // [key 0..127][dim]
  __shared__ short ldsV[E_ * VSTR];        // [dim][key 0..127]
  __shared__ short ldsP[2 * QT_ * PSTR];   // per-group 128-row P bands; aliased for combine

  float* ldsO = (float*)ldsP;              // combine: [128][OSTR]
  float* ldsL = (float*)ldsP + QT_ * OSTR; // combine: [128]

  const short* KbBase = Kb + (size_t)bh * L_ * E_;
  const short* VtBase = Vt + (size_t)bh * E_ * L_;

  // staging coords (512 threads): K rows krr,krr+64 cols kcc..+7; V rows vrr,vrr+32 keys vcc..+7
  const int krr = tid >> 3, kcc = (tid & 7) * 8;
  const int vrr = tid >> 4, vcc = (tid & 15) * 8;

  // ones B-frag: column 0 = 1.0bf16
  bs8 bOne;
  {
    short one = (l16 == 0) ? (short)0x3F80 : (short)0;
#pragma unroll
    for (int j = 0; j < 8; ++j) bOne[j] = one;
  }

  for (int phase = 0; phase < 2; ++phase) {
    const int qt = phase ? (15 - p) : p;
    const int q0 = qt * QT_;
    const int ns = qt + 1;   // super-tiles of 128 keys

    // ---- Q fragments: 2 strips of 16 rows (pre-scaled, exp2 domain) ----
    bs8 aQ[2][2];
#pragma unroll
    for (int st = 0; st < 2; ++st) {
      const int q = q0 + wl * 32 + st * 16 + l16;
      const float* qp = Q + (((size_t)b * L_ + q) * H_ + h) * E_ + quad * 8;
#pragma unroll
      for (int c = 0; c < 2; ++c) {
        float4 f0 = *(const float4*)(qp + c * 32);
        float4 f1 = *(const float4*)(qp + c * 32 + 4);
        bs8 a;
        a[0] = bf16of(f0.x * SCALE_LOG2E); a[1] = bf16of(f0.y * SCALE_LOG2E);
        a[2] = bf16of(f0.z * SCALE_LOG2E); a[3] = bf16of(f0.w * SCALE_LOG2E);
        a[4] = bf16of(f1.x * SCALE_LOG2E); a[5] = bf16of(f1.y * SCALE_LOG2E);
        a[6] = bf16of(f1.z * SCALE_LOG2E); a[7] = bf16of(f1.w * SCALE_LOG2E);
        aQ[st][c] = a;
      }
    }

    f32x4 accO[2][4];
    f32x4 accL[2];
#pragma unroll
    for (int st = 0; st < 2; ++st) {
      accL[st] = (f32x4){0.f, 0.f, 0.f, 0.f};
#pragma unroll
      for (int nt = 0; nt < 4; ++nt) accO[st][nt] = (f32x4){0.f, 0.f, 0.f, 0.f};
    }

    // ---- prefetch super-tile 0 into registers ----
    bs8 pfK[2], pfV[2];
#pragma unroll
    for (int i = 0; i < 2; ++i) {
      pfK[i] = *(const bs8*)(KbBase + (size_t)(krr + 64 * i) * E_ + kcc);
      pfV[i] = *(const bs8*)(VtBase + (size_t)(vrr + 32 * i) * L_ + vcc);
    }

    for (int sti = 0; sti < ns; ++sti) {
      const int k0 = sti * KTS;
      __syncthreads();   // previous super-tile's LDS reads complete

      // ---- commit prefetched super-tile to LDS ----
#pragma unroll
      for (int i = 0; i < 2; ++i) {
        *(bs8*)&ldsK[(krr + 64 * i) * KSTR + kcc] = pfK[i];
        *(bs8*)&ldsV[(vrr + 32 * i) * VSTR + vcc] = pfV[i];
      }
      // ---- prefetch next super-tile ----
      if (sti + 1 < ns) {
        const int kn = k0 + KTS;
#pragma unroll
        for (int i = 0; i < 2; ++i) {
          pfK[i] = *(const bs8*)(KbBase + (size_t)(kn + krr + 64 * i) * E_ + kcc);
          pfV[i] = *(const bs8*)(VtBase + (size_t)(vrr + 32 * i) * L_ + kn + vcc);
        }
      }
      __syncthreads();

      const int kb = k0 + g * 64;   // this wave's absolute 64-key window
      const int ko = g * 64;        // LDS key offset
      bool act[2];
      act[0] = (kb <= q0 + wl * 32 + 15);
      act[1] = (kb <= q0 + wl * 32 + 31);

      // ---- S = Q K^T; fused mask + exp2 + P-write per nt (keeps VGPR low) ----
#pragma unroll
      for (int nt = 0; nt < 4; ++nt) {
        bs8 bK0 = *(const bs8*)&ldsK[(ko + nt * 16 + l16) * KSTR + quad * 8];
        bs8 bK1 = *(const bs8*)&ldsK[(ko + nt * 16 + l16) * KSTR + 32 + quad * 8];
#pragma unroll
        for (int st = 0; st < 2; ++st) {
          if (act[st]) {
            f32x4 acc = (f32x4){0.f, 0.f, 0.f, 0.f};
            acc = __builtin_amdgcn_mfma_f32_16x16x32_bf16(aQ[st][0], bK0, acc, 0, 0, 0);
            acc = __builtin_amdgcn_mfma_f32_16x16x32_bf16(aQ[st][1], bK1, acc, 0, 0, 0);
            const int sbase = q0 + wl * 32 + st * 16;
            if (kb + 63 > sbase) {   // tile crosses strip diagonal
              const int qb = sbase + quad * 4;
              const int key = kb + nt * 16 + l16;
#pragma unroll
              for (int r = 0; r < 4; ++r)
                if (key > qb + r) acc[r] = NEG_INF;
            }
            const int rowb = g * QT_ + wl * 32 + st * 16 + quad * 4;
#pragma unroll
            for (int r = 0; r < 4; ++r)
              ldsP[(rowb + r) * PSTR + nt * 16 + l16] = bf16of(exp2f(acc[r]));
          }
        }
      }

      __threadfence_block();   // order wave-private P writes before A-frag reads

      // ---- read P frags; accumulate denominator (ones-MFMA) and O += P V ----
      bs8 aP[2][2];
#pragma unroll
      for (int st = 0; st < 2; ++st) {
        if (act[st]) {
          const int rowa = g * QT_ + wl * 32 + st * 16 + l16;
#pragma unroll
          for (int c = 0; c < 2; ++c)
            aP[st][c] = *(const bs8*)&ldsP[rowa * PSTR + c * 32 + quad * 8];
          accL[st] = __builtin_amdgcn_mfma_f32_16x16x32_bf16(aP[st][0], bOne, accL[st], 0, 0, 0);
          accL[st] = __builtin_amdgcn_mfma_f32_16x16x32_bf16(aP[st][1], bOne, accL[st], 0, 0, 0);
        }
      }
#pragma unroll
      for (int nt = 0; nt < 4; ++nt) {
        bs8 bV0 = *(const bs8*)&ldsV[(nt * 16 + l16) * VSTR + ko + quad * 8];
        bs8 bV1 = *(const bs8*)&ldsV[(nt * 16 + l16) * VSTR + ko + 32 + quad * 8];
#pragma unroll
        for (int st = 0; st < 2; ++st) {
          if (act[st]) {
            accO[st][nt] = __builtin_amdgcn_mfma_f32_16x16x32_bf16(aP[st][0], bV0, accO[st][nt], 0, 0, 0);
            accO[st][nt] = __builtin_amdgcn_mfma_f32_16x16x32_bf16(aP[st][1], bV1, accO[st][nt], 0, 0, 0);
          }
        }
      }
    }

    // ---- combine A+B partials (unnormalized exp2-domain sums add exactly) ----
    __syncthreads();   // all P reads done before aliasing ldsP as combine scratch
    if (g == 1) {
#pragma unroll
      for (int st = 0; st < 2; ++st) {
        const int rowb = wl * 32 + st * 16 + quad * 4;
#pragma unroll
        for (int nt = 0; nt < 4; ++nt)
#pragma unroll
          for (int r = 0; r < 4; ++r)
            ldsO[(rowb + r) * OSTR + nt * 16 + l16] = accO[st][nt][r];
        if (l16 == 0) {
#pragma unroll
          for (int r = 0; r < 4; ++r) ldsL[rowb + r] = accL[st][r];
        }
      }
    }
    __syncthreads();
    if (g == 0) {
#pragma unroll
      for (int st = 0; st < 2; ++st) {
        const int rowb = wl * 32 + st * 16 + quad * 4;
        float inv[4];
#pragma unroll
        for (int r = 0; r < 4; ++r) {
          float tot = accL[st][r] + ldsL[rowb + r];   // valid at l16==0
          inv[r] = 1.f / __shfl(tot, lane & 48, 64);  // broadcast from col-0 lane of quad
        }
#pragma unroll
        for (int nt = 0; nt < 4; ++nt) {
          const int q = q0 + rowb;                    // + r
          const int d = nt * 16 + l16;
          float* op = O + (((size_t)b * L_ + q) * H_ + h) * E_ + d;
#pragma unroll
          for (int r = 0; r < 4; ++r)
            op[(size_t)r * H_ * E_] = (accO[st][nt][r] + ldsO[(rowb + r) * OSTR + d]) * inv[r];
        }
      }
    }
  }
}

extern "C" void kernel_launch(void* const* d_in, const int* in_sizes, int n_in,
                              void* d_out, int out_size, void* d_ws, size_t ws_size,
                              hipStream_t stream) {
  (void)in_sizes; (void)n_in; (void)out_size; (void)ws_size;
  const float* Q = (const float*)d_in[0];
  const float* K = (const float*)d_in[1];
  const float* V = (const float*)d_in[2];
  float* Out = (float*)d_out;
  short* Kb = (short*)d_ws;                              // 16.78 MB
  short* Vt = Kb + (size_t)B_ * H_ * L_ * E_;            // +16.78 MB

  prep<<<1024 + 2048, 256, 0, stream>>>(K, V, Kb, Vt);
  flash_fwd<<<512, 512, 0, stream>>>(Q, Kb, Vt, Out);
}

// Round 4
// 205.520 us; speedup vs baseline: 1.1815x; 1.1815x over previous
//
#include <hip/hip_runtime.h>
#include <hip/hip_bf16.h>

typedef short bs8 __attribute__((ext_vector_type(8)));
typedef short bs4 __attribute__((ext_vector_type(4)));
typedef float f32x4 __attribute__((ext_vector_type(4)));
typedef float f32x16 __attribute__((ext_vector_type(16)));
typedef int i32x4 __attribute__((ext_vector_type(4)));

#define B_ 4
#define L_ 2048
#define H_ 16
#define E_ 64
#define KT_ 64    // keys per tile
#define KSTR 72   // LDS stride (shorts) for K/V rows
#define SCSTR 68  // f32 stride for epilogue transpose scratch
#define NEG_INF (-1e30f)
#define SCALE_LOG2E (0.125f * 1.44269504088896340736f)

__device__ __forceinline__ short bf16of(float x) {
  __hip_bfloat16 h = __float2bfloat16(x);
  return *reinterpret_cast<short*>(&h);
}

// ---------- Fused prepass (unchanged) ----------
// blocks [0,1024):    K fp32 [b,s,h,e] -> bf16 Kb [bh,s,e]   (grid-stride x8)
// blocks [1024,3072): V fp32 [b,s,h,e] -> bf16 Vt [bh,e,s]   (packed-u32 LDS transpose)
__global__ __launch_bounds__(256) void prep(const float* __restrict__ K,
                                            const float* __restrict__ V,
                                            short* __restrict__ Kb,
                                            short* __restrict__ Vt) {
  __shared__ unsigned int lt[64 * 35];   // [e][s_pair] packed 2x bf16
  const int tid = threadIdx.x;
  if (blockIdx.x < 1024) {
    size_t base = (size_t)blockIdx.x * 256 + tid;
#pragma unroll
    for (int i = 0; i < 8; ++i) {
      size_t g = base + (size_t)i * 262144;   // float4 index
      int e4 = g & 15;
      int h  = (g >> 4) & 15;
      int s  = (g >> 8) & 2047;
      int b  = (int)(g >> 19);
      float4 v = *(const float4*)(K + g * 4);
      bs4 o;
      o.x = bf16of(v.x); o.y = bf16of(v.y); o.z = bf16of(v.z); o.w = bf16of(v.w);
      *(bs4*)(Kb + (((size_t)(b * 16 + h) * L_ + s) * E_ + e4 * 4)) = o;
    }
  } else {
    int vb = blockIdx.x - 1024;   // 0..2047
    int st = vb & 31, bh = vb >> 5;
    int b = bh >> 4, h = bh & 15;
    int s0 = st * 64;
#pragma unroll
    for (int i = 0; i < 2; ++i) {
      int idx = i * 256 + tid;       // 0..511
      int sp = idx >> 4;             // s-pair 0..31
      int e4 = idx & 15;
      const float* p0 = V + (((size_t)b * L_ + s0 + 2 * sp) * H_ + h) * E_ + e4 * 4;
      float4 v0 = *(const float4*)p0;
      float4 v1 = *(const float4*)(p0 + H_ * E_);
      unsigned u;
      u = (unsigned short)bf16of(v0.x) | ((unsigned)(unsigned short)bf16of(v1.x) << 16);
      lt[(e4 * 4 + 0) * 35 + sp] = u;
      u = (unsigned short)bf16of(v0.y) | ((unsigned)(unsigned short)bf16of(v1.y) << 16);
      lt[(e4 * 4 + 1) * 35 + sp] = u;
      u = (unsigned short)bf16of(v0.z) | ((unsigned)(unsigned short)bf16of(v1.z) << 16);
      lt[(e4 * 4 + 2) * 35 + sp] = u;
      u = (unsigned short)bf16of(v0.w) | ((unsigned)(unsigned short)bf16of(v1.w) << 16);
      lt[(e4 * 4 + 3) * 35 + sp] = u;
    }
    __syncthreads();
#pragma unroll
    for (int i = 0; i < 2; ++i) {
      int idx = i * 256 + tid;
      int e  = idx >> 3;             // 0..63
      int s8 = idx & 7;              // 8-key group
      uint4 o;
      o.x = lt[e * 35 + s8 * 4 + 0];
      o.y = lt[e * 35 + s8 * 4 + 1];
      o.z = lt[e * 35 + s8 * 4 + 2];
      o.w = lt[e * 35 + s8 * 4 + 3];
      *(uint4*)(Vt + ((size_t)bh * E_ + e) * L_ + s0 + 8 * s8) = o;
    }
  }
}

// ---------- Main flash-attention kernel ----------
// Grid 1024, 256 threads (4 waves). Block = one 128-row q-tile; wave w owns
// rows [q0+32w, +32). Big-qt blocks dispatch first (LPT packing); dynamic
// scheduling absorbs imbalance at up to 4 blocks/CU.
// XCD decode: id&7 = XCD; each XCD works bh in [x*8, x*8+8) (K/V L2-local).
//
// Swapped QK^T (T12): S^T = K.Q^T via mfma_32x32x16 (A=K from LDS, B=Q in
// regs) -> lane holds P^T[key][q=lane&31] for 16 key-rows. Mask+exp2+pack
// in-register; PV B-frags built with cvt_pk (compiler-fused) + 4x
// v_permlane32_swap per 32-key subtile (distinct-value operands -> distinct
// regs guaranteed; identical-operand form miscompiles to vdst==src0, which
// was r3's inf bug in the denominator — now done via __shfl_xor).
// O^T = V^T.P^T (A=V^T from LDS). No P LDS round-trip, no fence, no
// ones-MFMA (denominator = f32 add tree + one shfl_xor; normalization needs
// no broadcast: every accO element's column is this lane's q).
// Epilogue: normalized O^T -> per-wave LDS scratch [q][d] -> coalesced
// float4 stores (4 full q-rows per instruction).
// 32x32x16 layouts (m74/m101 verified C/D; A/B per §B recipe):
//   A[m = lane&31][k = (lane>>5)*8 + j]
//   B[k = (lane>>5)*8 + j][n = lane&31]
//   C/D: col = lane&31, row = (reg&3) + 8*(reg>>2) + 4*(lane>>5)
__global__ __launch_bounds__(256, 3) void flash_fwd(const float* __restrict__ Q,
                                                    const short* __restrict__ Kb,
                                                    const short* __restrict__ Vt,
                                                    float* __restrict__ O) {
  const int id  = blockIdx.x;
  const int xcd = id & 7;
  const int j   = id >> 3;               // 0..127 within XCD
  const int qt  = 15 - (j & 15);         // big q-tiles first
  const int bh  = xcd * 8 + (j >> 4);
  const int b = bh >> 4, h = bh & 15;
  const int tid = threadIdx.x;
  const int w = tid >> 6;
  const int lane = tid & 63;
  const int l32 = lane & 31;
  const int hh  = lane >> 5;
  const int h8  = hh * 8;

  // ldsK/ldsV staging (18.4 KB) unioned with epilogue scratch (34 KB)
  __shared__ __align__(16) char smem[4 * 32 * SCSTR * 4];
  short* ldsK = (short*)smem;            // [64 keys][KSTR]
  short* ldsV = (short*)(smem + KT_ * KSTR * 2);   // [64 dims][KSTR]

  const short* KbBase = Kb + (size_t)bh * L_ * E_;
  const short* VtBase = Vt + (size_t)bh * E_ * L_;

  const int q0w = qt * 128 + w * 32;     // this wave's first q row
  const int nkt = 2 * (qt + 1);

  // staging coords: rows sr, sr+32; cols sc8..sc8+7
  const int sr = tid >> 3;
  const int sc8 = (tid & 7) * 8;

  // ---- Q B-frags: aQ[ks] covers dims ks*16 + h8 .. +7 (pre-scaled) ----
  bs8 aQ[4];
  {
    const float* qp = Q + (((size_t)b * L_ + q0w + l32) * H_ + h) * E_ + h8;
#pragma unroll
    for (int ks = 0; ks < 4; ++ks) {
      float4 f0 = *(const float4*)(qp + ks * 16);
      float4 f1 = *(const float4*)(qp + ks * 16 + 4);
      bs8 a;
      a[0] = bf16of(f0.x * SCALE_LOG2E); a[1] = bf16of(f0.y * SCALE_LOG2E);
      a[2] = bf16of(f0.z * SCALE_LOG2E); a[3] = bf16of(f0.w * SCALE_LOG2E);
      a[4] = bf16of(f1.x * SCALE_LOG2E); a[5] = bf16of(f1.y * SCALE_LOG2E);
      a[6] = bf16of(f1.z * SCALE_LOG2E); a[7] = bf16of(f1.w * SCALE_LOG2E);
      aQ[ks] = a;
    }
  }

  f32x16 accO[2];            // O^T: [dsub], row=d_local, col=q (this lane's)
#pragma unroll
  for (int d = 0; d < 2; ++d)
#pragma unroll
    for (int r = 0; r < 16; ++r) accO[d][r] = 0.f;
  float accL = 0.f;          // partial denominator (this lane's 16 key-rows)

  // ---- prefetch tile 0 ----
  bs8 pfK[2], pfV[2];
#pragma unroll
  for (int i = 0; i < 2; ++i) {
    pfK[i] = *(const bs8*)(KbBase + (size_t)(sr + 32 * i) * E_ + sc8);
    pfV[i] = *(const bs8*)(VtBase + (size_t)(sr + 32 * i) * L_ + sc8);
  }

  for (int kt = 0; kt < nkt; ++kt) {
    const int k0 = kt * KT_;
    __syncthreads();   // previous tile's LDS reads complete
#pragma unroll
    for (int i = 0; i < 2; ++i) {
      *(bs8*)&ldsK[(sr + 32 * i) * KSTR + sc8] = pfK[i];
      *(bs8*)&ldsV[(sr + 32 * i) * KSTR + sc8] = pfV[i];
    }
    if (kt + 1 < nkt) {
      const int kn = k0 + KT_;
#pragma unroll
      for (int i = 0; i < 2; ++i) {
        pfK[i] = *(const bs8*)(KbBase + (size_t)(kn + sr + 32 * i) * E_ + sc8);
        pfV[i] = *(const bs8*)(VtBase + (size_t)(sr + 32 * i) * L_ + kn + sc8);
      }
    }
    __syncthreads();

    if (k0 > q0w + 31) continue;         // wave fully masked for this tile
    const bool diag = (k0 + KT_ - 1 > q0w);

    // ---- per 32-key subtile: S^T, mask, exp2, denominator, pack ----
    bs8 pB[2][2];                        // [sub][ks'] PV B-frags
#pragma unroll
    for (int sub = 0; sub < 2; ++sub) {
      f32x16 cc;
#pragma unroll
      for (int r = 0; r < 16; ++r) cc[r] = 0.f;
#pragma unroll
      for (int ks = 0; ks < 4; ++ks) {
        bs8 aK = *(const bs8*)&ldsK[(sub * 32 + l32) * KSTR + ks * 16 + h8];
        cc = __builtin_amdgcn_mfma_f32_32x32x16_bf16(aK, aQ[ks], cc, 0, 0, 0);
      }
      if (diag) {
        const int qcol = q0w + l32;
#pragma unroll
        for (int r = 0; r < 16; ++r) {
          const int key = k0 + sub * 32 + ((r & 3) + 8 * (r >> 2) + 4 * hh);
          if (key > qcol) cc[r] = NEG_INF;
        }
      }
      float p[16];
#pragma unroll
      for (int r = 0; r < 16; ++r) p[r] = exp2f(cc[r]);
      accL += ((((p[0] + p[1]) + (p[2] + p[3])) + ((p[4] + p[5]) + (p[6] + p[7]))) +
               (((p[8] + p[9]) + (p[10] + p[11])) + ((p[12] + p[13]) + (p[14] + p[15]))));
      unsigned pk[8];
#pragma unroll
      for (int i = 0; i < 8; ++i)
        pk[i] = (unsigned)(unsigned short)bf16of(p[2 * i]) |
                ((unsigned)(unsigned short)bf16of(p[2 * i + 1]) << 16);
      // permlane32_swap: a' = {a.lo, b.lo}, b' = {a.hi, b.hi} (half-swap)
      // NOTE: operands must hold DISTINCT values (distinct vregs); identical
      // inputs tie both to one register -> vdst==src0 miscompile (r3 bug).
      unsigned w0 = pk[0], w2 = pk[2];
      asm("v_permlane32_swap_b32 %0, %1" : "+v"(w0), "+v"(w2));
      unsigned w1 = pk[1], w3 = pk[3];
      asm("v_permlane32_swap_b32 %0, %1" : "+v"(w1), "+v"(w3));
      unsigned w4 = pk[4], w6 = pk[6];
      asm("v_permlane32_swap_b32 %0, %1" : "+v"(w4), "+v"(w6));
      unsigned w5 = pk[5], w7 = pk[7];
      asm("v_permlane32_swap_b32 %0, %1" : "+v"(w5), "+v"(w7));
      i32x4 f0 = {(int)w0, (int)w1, (int)w2, (int)w3};
      i32x4 f1 = {(int)w4, (int)w5, (int)w6, (int)w7};
      pB[sub][0] = *(bs8*)&f0;
      pB[sub][1] = *(bs8*)&f1;
    }

    // ---- O^T += V^T . P^T ----
#pragma unroll
    for (int dsub = 0; dsub < 2; ++dsub) {
#pragma unroll
      for (int sub = 0; sub < 2; ++sub) {
#pragma unroll
        for (int ks = 0; ks < 2; ++ks) {
          bs8 aV = *(const bs8*)&ldsV[(dsub * 32 + l32) * KSTR + sub * 32 + ks * 16 + h8];
          accO[dsub] = __builtin_amdgcn_mfma_f32_32x32x16_bf16(aV, pB[sub][ks], accO[dsub], 0, 0, 0);
        }
      }
    }
  }

  // ---- denominator: add partner half-wave's partial (lane ^ 32) ----
  const float inv = 1.f / (accL + __shfl_xor(accL, 32, 64));

  // ---- epilogue: normalized O^T -> per-wave LDS [q][d] -> coalesced store ----
  __syncthreads();   // all waves done reading ldsK/ldsV before scratch reuse
  float* scb = (float*)(smem + w * (32 * SCSTR * 4));
#pragma unroll
  for (int dsub = 0; dsub < 2; ++dsub)
#pragma unroll
    for (int g = 0; g < 4; ++g) {
      f32x4 vv = {accO[dsub][4 * g + 0] * inv, accO[dsub][4 * g + 1] * inv,
                  accO[dsub][4 * g + 2] * inv, accO[dsub][4 * g + 3] * inv};
      *(f32x4*)&scb[(size_t)l32 * SCSTR + dsub * 32 + 8 * g + 4 * hh] = vv;
    }
#pragma unroll
  for (int jj = 0; jj < 8; ++jj) {
    const int qq = jj * 4 + (lane >> 4);   // 4 full q-rows per instruction
    const int d0 = (lane & 15) * 4;
    f32x4 ov = *(const f32x4*)&scb[(size_t)qq * SCSTR + d0];
    float* op = O + (((size_t)b * L_ + q0w + qq) * H_ + h) * E_ + d0;
    *(f32x4*)op = ov;
  }
}

extern "C" void kernel_launch(void* const* d_in, const int* in_sizes, int n_in,
                              void* d_out, int out_size, void* d_ws, size_t ws_size,
                              hipStream_t stream) {
  (void)in_sizes; (void)n_in; (void)out_size; (void)ws_size;
  const float* Q = (const float*)d_in[0];
  const float* K = (const float*)d_in[1];
  const float* V = (const float*)d_in[2];
  float* Out = (float*)d_out;
  short* Kb = (short*)d_ws;                              // 16.78 MB
  short* Vt = Kb + (size_t)B_ * H_ * L_ * E_;            // +16.78 MB

  prep<<<1024 + 2048, 256, 0, stream>>>(K, V, Kb, Vt);
  flash_fwd<<<1024, 256, 0, stream>>>(Q, Kb, Vt, Out);
}

// Round 5
// 201.280 us; speedup vs baseline: 1.2064x; 1.0211x over previous
//
#include <hip/hip_runtime.h>
#include <hip/hip_bf16.h>

typedef short bs8 __attribute__((ext_vector_type(8)));
typedef short bs4 __attribute__((ext_vector_type(4)));
typedef float f32x4 __attribute__((ext_vector_type(4)));
typedef float f32x16 __attribute__((ext_vector_type(16)));
typedef int i32x4 __attribute__((ext_vector_type(4)));

#define B_ 4
#define L_ 2048
#define H_ 16
#define E_ 64
#define KT_ 64    // keys per staged tile (two 32-key halves, one per wave-group)
#define KSTR 72   // LDS stride (shorts) for K/V rows
#define SCSTR 68  // f32 stride for combine/transpose scratch
#define NEG_INF (-1e30f)
#define SCALE_LOG2E (0.125f * 1.44269504088896340736f)

__device__ __forceinline__ short bf16of(float x) {
  __hip_bfloat16 h = __float2bfloat16(x);
  return *reinterpret_cast<short*>(&h);
}

// ---------- Fused prepass (unchanged) ----------
// blocks [0,1024):    K fp32 [b,s,h,e] -> bf16 Kb [bh,s,e]   (grid-stride x8)
// blocks [1024,3072): V fp32 [b,s,h,e] -> bf16 Vt [bh,e,s]   (packed-u32 LDS transpose)
__global__ __launch_bounds__(256) void prep(const float* __restrict__ K,
                                            const float* __restrict__ V,
                                            short* __restrict__ Kb,
                                            short* __restrict__ Vt) {
  __shared__ unsigned int lt[64 * 35];   // [e][s_pair] packed 2x bf16
  const int tid = threadIdx.x;
  if (blockIdx.x < 1024) {
    size_t base = (size_t)blockIdx.x * 256 + tid;
#pragma unroll
    for (int i = 0; i < 8; ++i) {
      size_t g = base + (size_t)i * 262144;   // float4 index
      int e4 = g & 15;
      int h  = (g >> 4) & 15;
      int s  = (g >> 8) & 2047;
      int b  = (int)(g >> 19);
      float4 v = *(const float4*)(K + g * 4);
      bs4 o;
      o.x = bf16of(v.x); o.y = bf16of(v.y); o.z = bf16of(v.z); o.w = bf16of(v.w);
      *(bs4*)(Kb + (((size_t)(b * 16 + h) * L_ + s) * E_ + e4 * 4)) = o;
    }
  } else {
    int vb = blockIdx.x - 1024;   // 0..2047
    int st = vb & 31, bh = vb >> 5;
    int b = bh >> 4, h = bh & 15;
    int s0 = st * 64;
#pragma unroll
    for (int i = 0; i < 2; ++i) {
      int idx = i * 256 + tid;       // 0..511
      int sp = idx >> 4;             // s-pair 0..31
      int e4 = idx & 15;
      const float* p0 = V + (((size_t)b * L_ + s0 + 2 * sp) * H_ + h) * E_ + e4 * 4;
      float4 v0 = *(const float4*)p0;
      float4 v1 = *(const float4*)(p0 + H_ * E_);
      unsigned u;
      u = (unsigned short)bf16of(v0.x) | ((unsigned)(unsigned short)bf16of(v1.x) << 16);
      lt[(e4 * 4 + 0) * 35 + sp] = u;
      u = (unsigned short)bf16of(v0.y) | ((unsigned)(unsigned short)bf16of(v1.y) << 16);
      lt[(e4 * 4 + 1) * 35 + sp] = u;
      u = (unsigned short)bf16of(v0.z) | ((unsigned)(unsigned short)bf16of(v1.z) << 16);
      lt[(e4 * 4 + 2) * 35 + sp] = u;
      u = (unsigned short)bf16of(v0.w) | ((unsigned)(unsigned short)bf16of(v1.w) << 16);
      lt[(e4 * 4 + 3) * 35 + sp] = u;
    }
    __syncthreads();
#pragma unroll
    for (int i = 0; i < 2; ++i) {
      int idx = i * 256 + tid;
      int e  = idx >> 3;             // 0..63
      int s8 = idx & 7;              // 8-key group
      uint4 o;
      o.x = lt[e * 35 + s8 * 4 + 0];
      o.y = lt[e * 35 + s8 * 4 + 1];
      o.z = lt[e * 35 + s8 * 4 + 2];
      o.w = lt[e * 35 + s8 * 4 + 3];
      *(uint4*)(Vt + ((size_t)bh * E_ + e) * L_ + s0 + 8 * s8) = o;
    }
  }
}

// ---------- Main flash-attention kernel ----------
// Grid 1024, 256 threads (4 waves). Block = 64 q-rows, handling q-tile pair
// {p, 31-p} in two phases: (p+1)+(32-p) = 33 tiles -> EVERY block identical
// work (r4 lesson: grid == resident capacity means no backfill; per-CU
// balance must be structural). 4 blocks/CU resident = 16 waves/CU.
// Wave (g,s): s = row strip [q0+32s, +32), g = key half-group; both groups
// compute the SAME staged 64-key tile concurrently (g's 32-key half), so no
// intra-block alternation. Unnormalized exp2-domain partials (accO, accL)
// combined across g via LDS at phase end (exact: same denominators add).
// XCD decode: id&7 = XCD; each XCD works bh in [x*8, x*8+8) (K/V L2-local).
//
// Swapped QK^T (T12): S^T = K.Q^T via mfma_32x32x16 (A=K from LDS, B=Q in
// regs) -> lane holds P^T[key][q=lane&31] for 16 key-rows of its half.
// Mask+exp2+pack in-register; PV B-frags via cvt_pk (compiler-fused) + 2x
// v_permlane32_swap (distinct-value operands only -- identical inputs tie
// to one vreg -> vdst==src0 miscompile, the r3 inf bug).
// O^T = V^T.P^T (A=V^T from LDS). No P LDS round-trip, no fence.
// 32x32x16 layouts (m74/m101 verified):
//   A[m = lane&31][k = (lane>>5)*8 + j]
//   B[k = (lane>>5)*8 + j][n = lane&31]
//   C/D: col = lane&31, row = (reg&3) + 8*(reg>>2) + 4*(lane>>5)
__global__ __launch_bounds__(256, 4) void flash_fwd(const float* __restrict__ Q,
                                                    const short* __restrict__ Kb,
                                                    const short* __restrict__ Vt,
                                                    float* __restrict__ O) {
  const int id  = blockIdx.x;
  const int xcd = id & 7;
  const int j   = id >> 3;               // 0..127 within XCD
  const int bh  = xcd * 8 + (j >> 4);
  const int p   = j & 15;                // pair {p, 31-p}
  const int b = bh >> 4, h = bh & 15;
  const int tid = threadIdx.x;
  const int w = tid >> 6;
  const int g = w >> 1;                  // key half-group: keys [k0+32g, +32)
  const int s = w & 1;                   // row strip
  const int lane = tid & 63;
  const int l32 = lane & 31;
  const int hh  = lane >> 5;
  const int h8  = hh * 8;

  // tile staging (18.4 KB) unioned with combine/transpose scratch (17.7 KB)
  __shared__ __align__(16) char smem[18432];
  short* ldsK = (short*)smem;                       // [64 keys][KSTR]
  short* ldsV = (short*)(smem + KT_ * KSTR * 2);    // [64 dims][KSTR]
  float* scb  = (float*)smem;                       // combine scratch

  const short* KbBase = Kb + (size_t)bh * L_ * E_;
  const short* VtBase = Vt + (size_t)bh * E_ * L_;

  // staging coords: rows sr, sr+32; cols sc8..sc8+7 (r4-verified pattern)
  const int sr = tid >> 3;
  const int sc8 = (tid & 7) * 8;

  for (int phase = 0; phase < 2; ++phase) {
    const int qt  = phase ? (31 - p) : p;
    const int q0w = qt * 64 + 32 * s;    // this wave's first q row
    const int nkt = qt + 1;

    // ---- Q B-frags: aQ[ks] covers dims ks*16 + h8 .. +7 (pre-scaled) ----
    bs8 aQ[4];
    {
      const float* qp = Q + (((size_t)b * L_ + q0w + l32) * H_ + h) * E_ + h8;
#pragma unroll
      for (int ks = 0; ks < 4; ++ks) {
        float4 f0 = *(const float4*)(qp + ks * 16);
        float4 f1 = *(const float4*)(qp + ks * 16 + 4);
        bs8 a;
        a[0] = bf16of(f0.x * SCALE_LOG2E); a[1] = bf16of(f0.y * SCALE_LOG2E);
        a[2] = bf16of(f0.z * SCALE_LOG2E); a[3] = bf16of(f0.w * SCALE_LOG2E);
        a[4] = bf16of(f1.x * SCALE_LOG2E); a[5] = bf16of(f1.y * SCALE_LOG2E);
        a[6] = bf16of(f1.z * SCALE_LOG2E); a[7] = bf16of(f1.w * SCALE_LOG2E);
        aQ[ks] = a;
      }
    }

    f32x16 accO[2];            // O^T partial (this g's keys): [dsub]
#pragma unroll
    for (int d = 0; d < 2; ++d)
#pragma unroll
      for (int r = 0; r < 16; ++r) accO[d][r] = 0.f;
    float accL = 0.f;          // denominator partial

    // ---- prefetch tile 0 ----
    bs8 pfK[2], pfV[2];
#pragma unroll
    for (int i = 0; i < 2; ++i) {
      pfK[i] = *(const bs8*)(KbBase + (size_t)(sr + 32 * i) * E_ + sc8);
      pfV[i] = *(const bs8*)(VtBase + (size_t)(sr + 32 * i) * L_ + sc8);
    }

    for (int kt = 0; kt < nkt; ++kt) {
      const int k0 = kt * KT_;
      __syncthreads();   // previous tile's LDS reads (or scratch reads) done
#pragma unroll
      for (int i = 0; i < 2; ++i) {
        *(bs8*)&ldsK[(sr + 32 * i) * KSTR + sc8] = pfK[i];
        *(bs8*)&ldsV[(sr + 32 * i) * KSTR + sc8] = pfV[i];
      }
      if (kt + 1 < nkt) {
        const int kn = k0 + KT_;
#pragma unroll
        for (int i = 0; i < 2; ++i) {
          pfK[i] = *(const bs8*)(KbBase + (size_t)(kn + sr + 32 * i) * E_ + sc8);
          pfV[i] = *(const bs8*)(VtBase + (size_t)(sr + 32 * i) * L_ + kn + sc8);
        }
      }
      __syncthreads();

      const int kb = k0 + 32 * g;          // this wave's 32-key half
      if (kb <= q0w + 31) {                // not fully masked
        const bool diag = (kb + 31 > q0w);

        // ---- S^T = K.Q^T on this half; mask; exp2; denominator; pack ----
        f32x16 cc;
#pragma unroll
        for (int r = 0; r < 16; ++r) cc[r] = 0.f;
#pragma unroll
        for (int ks = 0; ks < 4; ++ks) {
          bs8 aK = *(const bs8*)&ldsK[(32 * g + l32) * KSTR + ks * 16 + h8];
          cc = __builtin_amdgcn_mfma_f32_32x32x16_bf16(aK, aQ[ks], cc, 0, 0, 0);
        }
        if (diag) {
          const int qcol = q0w + l32;
#pragma unroll
          for (int r = 0; r < 16; ++r) {
            const int key = kb + ((r & 3) + 8 * (r >> 2) + 4 * hh);
            if (key > qcol) cc[r] = NEG_INF;
          }
        }
        float pv[16];
#pragma unroll
        for (int r = 0; r < 16; ++r) pv[r] = exp2f(cc[r]);
        accL += ((((pv[0] + pv[1]) + (pv[2] + pv[3])) + ((pv[4] + pv[5]) + (pv[6] + pv[7]))) +
                 (((pv[8] + pv[9]) + (pv[10] + pv[11])) + ((pv[12] + pv[13]) + (pv[14] + pv[15]))));
        unsigned pk[8];
#pragma unroll
        for (int i = 0; i < 8; ++i)
          pk[i] = (unsigned)(unsigned short)bf16of(pv[2 * i]) |
                  ((unsigned)(unsigned short)bf16of(pv[2 * i + 1]) << 16);
        unsigned w0 = pk[0], w2 = pk[2];
        asm("v_permlane32_swap_b32 %0, %1" : "+v"(w0), "+v"(w2));
        unsigned w1 = pk[1], w3 = pk[3];
        asm("v_permlane32_swap_b32 %0, %1" : "+v"(w1), "+v"(w3));
        unsigned w4 = pk[4], w6 = pk[6];
        asm("v_permlane32_swap_b32 %0, %1" : "+v"(w4), "+v"(w6));
        unsigned w5 = pk[5], w7 = pk[7];
        asm("v_permlane32_swap_b32 %0, %1" : "+v"(w5), "+v"(w7));
        i32x4 f0 = {(int)w0, (int)w1, (int)w2, (int)w3};
        i32x4 f1 = {(int)w4, (int)w5, (int)w6, (int)w7};
        bs8 pB0 = *(bs8*)&f0;
        bs8 pB1 = *(bs8*)&f1;

        // ---- O^T += V^T . P^T (this g's 32 keys) ----
#pragma unroll
        for (int dsub = 0; dsub < 2; ++dsub) {
          bs8 aV0 = *(const bs8*)&ldsV[(dsub * 32 + l32) * KSTR + 32 * g + h8];
          bs8 aV1 = *(const bs8*)&ldsV[(dsub * 32 + l32) * KSTR + 32 * g + 16 + h8];
          accO[dsub] = __builtin_amdgcn_mfma_f32_32x32x16_bf16(aV0, pB0, accO[dsub], 0, 0, 0);
          accO[dsub] = __builtin_amdgcn_mfma_f32_32x32x16_bf16(aV1, pB1, accO[dsub], 0, 0, 0);
        }
      }
    }

    // ---- combine across g (unnormalized partials add exactly), store ----
    const float Lf = accL + __shfl_xor(accL, 32, 64);
    __syncthreads();   // all tile LDS reads done; smem -> scratch
    float* scbO = scb + s * (32 * SCSTR);
    float* scbL = scb + 2 * (32 * SCSTR) + s * 32;
    if (g == 1) {
#pragma unroll
      for (int dsub = 0; dsub < 2; ++dsub)
#pragma unroll
        for (int q4 = 0; q4 < 4; ++q4) {
          f32x4 vv = {accO[dsub][4 * q4 + 0], accO[dsub][4 * q4 + 1],
                      accO[dsub][4 * q4 + 2], accO[dsub][4 * q4 + 3]};
          *(f32x4*)&scbO[(size_t)l32 * SCSTR + dsub * 32 + 8 * q4 + 4 * hh] = vv;
        }
      if (hh == 0) scbL[l32] = Lf;
    }
    __syncthreads();
    if (g == 0) {
      const float inv = 1.f / (Lf + scbL[l32]);
#pragma unroll
      for (int dsub = 0; dsub < 2; ++dsub)
#pragma unroll
        for (int q4 = 0; q4 < 4; ++q4) {
          float* ptr = &scbO[(size_t)l32 * SCSTR + dsub * 32 + 8 * q4 + 4 * hh];
          f32x4 ov = *(const f32x4*)ptr;
          f32x4 vv = {(accO[dsub][4 * q4 + 0] + ov.x) * inv,
                      (accO[dsub][4 * q4 + 1] + ov.y) * inv,
                      (accO[dsub][4 * q4 + 2] + ov.z) * inv,
                      (accO[dsub][4 * q4 + 3] + ov.w) * inv};
          *(f32x4*)ptr = vv;
        }
      // transposed coalesced store: 4 full q-rows per instruction
#pragma unroll
      for (int jj = 0; jj < 8; ++jj) {
        const int qq = jj * 4 + (lane >> 4);
        const int d0 = (lane & 15) * 4;
        f32x4 ov = *(const f32x4*)&scbO[(size_t)qq * SCSTR + d0];
        float* op = O + (((size_t)b * L_ + qt * 64 + 32 * s + qq) * H_ + h) * E_ + d0;
        *(f32x4*)op = ov;
      }
    }
  }
}

extern "C" void kernel_launch(void* const* d_in, const int* in_sizes, int n_in,
                              void* d_out, int out_size, void* d_ws, size_t ws_size,
                              hipStream_t stream) {
  (void)in_sizes; (void)n_in; (void)out_size; (void)ws_size;
  const float* Q = (const float*)d_in[0];
  const float* K = (const float*)d_in[1];
  const float* V = (const float*)d_in[2];
  float* Out = (float*)d_out;
  short* Kb = (short*)d_ws;                              // 16.78 MB
  short* Vt = Kb + (size_t)B_ * H_ * L_ * E_;            // +16.78 MB

  prep<<<1024 + 2048, 256, 0, stream>>>(K, V, Kb, Vt);
  flash_fwd<<<1024, 256, 0, stream>>>(Q, Kb, Vt, Out);
}